// Round 20
// baseline (293.733 us; speedup 1.0000x reference)
//
#include <hip/hip_runtime.h>
#include <cstdint>
#include <cstddef>

#define TDIM 4096       // B*S tokens
#define DDIM 1024
#define HDIM 4096
#define EDIM 8
#define CAPD 2048
#define NSLOT 8192      // T*K
#define NROUTERBLK 1024

typedef _Float16 f16;
typedef _Float16 f16x2 __attribute__((ext_vector_type(2)));
typedef _Float16 f16x4 __attribute__((ext_vector_type(4)));
typedef _Float16 f16x8 __attribute__((ext_vector_type(8)));
typedef float f32x4 __attribute__((ext_vector_type(4)));

__device__ __forceinline__ void gload16(const void* g, void* l) {
  __builtin_amdgcn_global_load_lds(
      (const __attribute__((address_space(1))) unsigned int*)g,
      (__attribute__((address_space(3))) unsigned int*)l, 16, 0, 0);
}

__device__ __forceinline__ float gelu_fast(float x) {
  float y = 1.5957691216057308f * (x + 0.044715f * x * x * x);
  y = fminf(y, 60.f);
  float e = __expf(y);
  return x * e * __builtin_amdgcn_rcpf(e + 1.f);
}

// ------- transpose+cvt r20: gload_lds staging + source XOR-swizzle, conflict-free readout -------
// 64x64 f32 tile (16KB, 8 blocks/CU). Stage: async global->LDS, source col-slot
// pre-swizzled slot' = (s&8)|((s^(row>>3))&7) (involution). Readout: thread (c=idx>>3,
// w=idx&7) gathers rows 8w..8w+7 of column c -> bank = 4*((c>>2)^w)+(c&3): 2 lanes/bank
// = FREE (m136). Write: f16x8 16B/lane, 128B segments. Flat grid: b>>13 = which weight.
__global__ __launch_bounds__(256, 8)
void transpose2_cvt(const float* __restrict__ w1, f16* __restrict__ w1t,
                    const float* __restrict__ w2, f16* __restrict__ w2t) {
  __shared__ __align__(128) char smem[16384];
  const int b = blockIdx.x;
  const int half = b >> 13, within = b & 8191;
  const int e = within >> 10, tile = within & 1023;
  const float* src; f16* dst; int R, C, rt, ct;
  if (half == 0) { src = w1; dst = w1t; R = DDIM; C = HDIM; ct = tile & 63; rt = tile >> 6; }
  else           { src = w2; dst = w2t; R = HDIM; C = DDIM; ct = tile & 15; rt = tile >> 4; }
  const int tid = threadIdx.x, wv = tid >> 6;
  const int r0 = rt * 64, c0 = ct * 64;
  const float* s = src + (size_t)e * R * C + (size_t)r0 * C + c0;
  f16* d = dst + (size_t)e * R * C + (size_t)c0 * R + r0;
  #pragma unroll
  for (int i = 0; i < 4; ++i) {
    const int chunk = i * 256 + tid;
    const int row = chunk >> 4, s4 = chunk & 15;
    const int sl = (s4 & 8) | ((s4 ^ (row >> 3)) & 7);
    gload16(s + (size_t)row * C + sl * 4, smem + i * 4096 + wv * 1024);
  }
  __syncthreads();
  #pragma unroll
  for (int it = 0; it < 2; ++it) {
    const int idx = it * 256 + tid;
    const int c = idx >> 3, w = idx & 7;
    const int slotc = ((c >> 2) & 8) | (((c >> 2) ^ w) & 7);
    const int cb4 = (c & 3) * 4;
    f16x8 o;
    #pragma unroll
    for (int j = 0; j < 8; ++j) {
      const float v = *(const float*)(smem + (8 * w + j) * 256 + slotc * 16 + cb4);
      o[j] = (f16)v;
    }
    *(f16x8*)(d + (size_t)c * R + 8 * w) = o;
  }
}

// ---------------- router ----------------
__global__ void router_k(const float* __restrict__ x, const float* __restrict__ rw,
                         int* __restrict__ eidx, float* __restrict__ gates,
                         float* __restrict__ bps) {
  __shared__ float lrw[EDIM * DDIM];
  __shared__ float wps[4][EDIM];
  const int tid = threadIdx.x, lane = tid & 63, wv = tid >> 6;
  for (int i = tid; i < EDIM * DDIM; i += 256) lrw[i] = rw[i];
  __syncthreads();
  const int t = blockIdx.x * 4 + wv;
  float acc[EDIM];
  #pragma unroll
  for (int e = 0; e < EDIM; ++e) acc[e] = 0.f;
  const float* xr = x + (size_t)t * DDIM;
  #pragma unroll
  for (int j = 0; j < DDIM / 64; ++j) {
    float xv = xr[j * 64 + lane];
    #pragma unroll
    for (int e = 0; e < EDIM; ++e) acc[e] += xv * lrw[e * DDIM + j * 64 + lane];
  }
  #pragma unroll
  for (int off = 32; off >= 1; off >>= 1) {
    #pragma unroll
    for (int e = 0; e < EDIM; ++e) acc[e] += __shfl_xor(acc[e], off);
  }
  float mx = acc[0];
  #pragma unroll
  for (int e = 1; e < EDIM; ++e) mx = fmaxf(mx, acc[e]);
  float p[EDIM], s = 0.f;
  #pragma unroll
  for (int e = 0; e < EDIM; ++e) { p[e] = expf(acc[e] - mx); s += p[e]; }
  float inv = 1.f / s;
  #pragma unroll
  for (int e = 0; e < EDIM; ++e) p[e] *= inv;
  int i1 = 0; float p1 = p[0];
  #pragma unroll
  for (int e = 1; e < EDIM; ++e) if (p[e] > p1) { p1 = p[e]; i1 = e; }
  int i2 = (i1 == 0) ? 1 : 0; float p2 = p[i2];
  #pragma unroll
  for (int e = 0; e < EDIM; ++e) if (e != i1 && p[e] > p2) { p2 = p[e]; i2 = e; }
  float gs = 1.f / (p1 + p2);
  if (lane == 0) {
    eidx[2 * t] = i1; eidx[2 * t + 1] = i2;
    gates[2 * t] = p1 * gs; gates[2 * t + 1] = p2 * gs;
    #pragma unroll
    for (int e = 0; e < EDIM; ++e) wps[wv][e] = p[e];
  }
  __syncthreads();
  if (tid < EDIM)
    bps[blockIdx.x * EDIM + tid] = wps[0][tid] + wps[1][tid] + wps[2][tid] + wps[3][tid];
}

// ---------------- per-chunk expert histogram ----------------
__global__ void count_k(const int* __restrict__ eidx, int* __restrict__ cc) {
  __shared__ int h[EDIM];
  const int tid = threadIdx.x;
  if (tid < EDIM) h[tid] = 0;
  __syncthreads();
  atomicAdd(&h[eidx[blockIdx.x * 256 + tid]], 1);
  __syncthreads();
  if (tid < EDIM) cc[blockIdx.x * EDIM + tid] = h[tid];
}

// ---------------- scan chunks, totals, lb_loss ----------------
__global__ void scan_k(const int* __restrict__ cc, const float* __restrict__ bps,
                       int* __restrict__ cb, int* __restrict__ counts,
                       int* __restrict__ rowsNeeded, float* __restrict__ lb_out) {
  __shared__ float red[32][EDIM];
  __shared__ int cnt_s[EDIM];
  const int tid = threadIdx.x;
  const int e = tid & 7, g = tid >> 3;
  float s = 0.f;
  for (int j = 0; j < 32; ++j) s += bps[(g + 32 * j) * EDIM + e];
  red[g][e] = s;
  __syncthreads();
  for (int st = 16; st >= 1; st >>= 1) {
    if (g < st) red[g][e] += red[g + st][e];
    __syncthreads();
  }
  if (tid < EDIM) {
    int base = 0;
    for (int c = 0; c < 32; ++c) { cb[c * EDIM + tid] = base; base += cc[c * EDIM + tid]; }
    counts[tid] = base;
    rowsNeeded[tid] = base < CAPD ? base : CAPD;
    cnt_s[tid] = base;
  }
  __syncthreads();
  if (tid == 0) {
    float lb = 0.f;
    for (int ee = 0; ee < EDIM; ++ee)
      lb += (red[0][ee] / (float)TDIM) * ((float)cnt_s[ee] / (float)NSLOT);
    lb_out[0] = lb * (float)EDIM;
  }
}

// ---------------- per-slot position via wave ballots (deterministic) ----------------
__global__ void pos_k(const int* __restrict__ eidx, const float* __restrict__ gates,
                      const int* __restrict__ cb, int* __restrict__ posa,
                      float* __restrict__ wslot) {
  __shared__ int wcnt[4][EDIM];
  const int tid = threadIdx.x, lane = tid & 63, wv = tid >> 6;
  const int slot = blockIdx.x * 256 + tid;
  const int e = eidx[slot];
  const unsigned long long below = (1ull << lane) - 1ull;
  int wavepos = 0;
  #pragma unroll
  for (int ee = 0; ee < EDIM; ++ee) {
    unsigned long long m = __ballot(e == ee);
    if (lane == 0) wcnt[wv][ee] = __popcll(m);
    if (e == ee) wavepos = __popcll(m & below);
  }
  __syncthreads();
  int off = 0;
  for (int w = 0; w < wv; ++w) off += wcnt[w][e];
  const int pos = cb[blockIdx.x * EDIM + e] + off + wavepos;
  posa[slot] = pos;
  wslot[slot] = (pos < CAPD) ? gates[slot] : 0.f;
}

// ---------------- scatter: one block per TOKEN, f16x8 writes, both slots ----------------
__global__ void scatter2_k(const float* __restrict__ x, const int* __restrict__ eidx,
                           const int* __restrict__ posa, f16* __restrict__ buf) {
  const int t = blockIdx.x, lane = threadIdx.x;   // 64 threads
  const int s0 = 2 * t, s1 = 2 * t + 1;
  const int p0 = posa[s0], p1 = posa[s1];
  const int e0 = eidx[s0], e1 = eidx[s1];
  const float4* src = (const float4*)(x + (size_t)t * DDIM);
  f16x8* d0 = (f16x8*)(buf + ((size_t)e0 * CAPD + p0) * DDIM);
  f16x8* d1 = (f16x8*)(buf + ((size_t)e1 * CAPD + p1) * DDIM);
  const bool w0 = p0 < CAPD, w1 = p1 < CAPD;
  #pragma unroll
  for (int j = 0; j < 2; ++j) {
    float4 a = src[j * 128 + lane * 2];
    float4 b = src[j * 128 + lane * 2 + 1];
    f16x8 o;
    o[0] = (f16)a.x; o[1] = (f16)a.y; o[2] = (f16)a.z; o[3] = (f16)a.w;
    o[4] = (f16)b.x; o[5] = (f16)b.y; o[6] = (f16)b.z; o[7] = (f16)b.w;
    if (w0) d0[j * 64 + lane] = o;
    if (w1) d1[j * 64 + lane] = o;
  }
}

// ============ 128x128 f16 MFMA GEMM — r14 structure (best verified) ============
// Single 32KB buffer, full-drain __syncthreads K-loop, 4 blocks/CU, T2 swizzle,
// L2-banded 1-D grid (e = wg&7 -> XCD-affine; NTH band keeps per-expert B set <= 4MB).
#define STAGE(hh, g) do { \
    const f16* s_ = sP[hh] + (g) * 64; \
    char* d_ = smem + (hh) * 8192 + wv * 1024; \
    gload16(s_, d_); \
    gload16(s_ + (size_t)32 * LD, d_ + 4096); \
  } while (0)

template<int KLEN, int LD, int N, int GELU, int NTH, int NKS, int NMT>
__global__ __launch_bounds__(256, 4)
void gemm128s(const f16* __restrict__ A, const f16* __restrict__ Bt,
              const float* __restrict__ bias, f16* __restrict__ C, size_t pstride,
              const int* __restrict__ rowsNeeded) {
  constexpr int NTT = KLEN / 64;           // K-tiles
  __shared__ __align__(128) char smem[32768];
  const int wg = blockIdx.x;
  const int e = wg & 7;
  const int r = wg >> 3;
  const int ntl = r % NTH;
  const int ks = (r / NTH) % NKS;
  const int mt = (r / (NTH * NKS)) % NMT;
  const int nth = r / (NTH * NKS * NMT);
  const int nt = nth * NTH + ntl;
  if (mt * 128 >= rowsNeeded[e]) return;
  const int tid = threadIdx.x, lane = tid & 63, wv = tid >> 6;   // wv 0..3
  const int wr = wv >> 1, wc = wv & 1;     // 2 x 2 wave grid, per-wave 64x64 out
  const int ro = lane & 15, q4 = (lane >> 4) * 4;
  const int ko0b = (lane >> 4) * 16;       // k-offset bytes within 128B row
  const f16* aBase = A + ((size_t)e * CAPD + (size_t)mt * 128) * LD + (size_t)ks * KLEN;
  const f16* bBase = Bt + ((size_t)e * N + (size_t)nt * 128) * LD + (size_t)ks * KLEN;
  const int row0 = tid >> 3;               // 0..31 (second gload does row0+32)
  const int sw0 = ((tid & 7) ^ (row0 & 7)) * 8;   // pre-swizzled source col (elements)

  const f16* sP[4];
  sP[0] = aBase + (size_t)row0 * LD + sw0;
  sP[1] = sP[0] + (size_t)64 * LD;
  sP[2] = bBase + (size_t)row0 * LD + sw0;
  sP[3] = sP[2] + (size_t)64 * LD;

  // hoisted LDS read byte-offsets
  int aoffs[4][2], boffs[4][2];
  #pragma unroll
  for (int m = 0; m < 4; ++m)
    #pragma unroll
    for (int k = 0; k < 2; ++k) {
      const int rh = wr * 64 + m * 16 + ro;
      aoffs[m][k] = rh * 128 + ((k * 64 + ko0b) ^ ((rh & 7) << 4));
      const int rb = wc * 64 + m * 16 + ro;
      boffs[m][k] = 16384 + rb * 128 + ((k * 64 + ko0b) ^ ((rb & 7) << 4));
    }

  f32x4 acc[4][4];
  #pragma unroll
  for (int m = 0; m < 4; ++m)
    #pragma unroll
    for (int n = 0; n < 4; ++n) acc[m][n] = (f32x4){0.f, 0.f, 0.f, 0.f};

  #pragma unroll 1
  for (int t = 0; t < NTT; ++t) {
    STAGE(0, t); STAGE(1, t); STAGE(2, t); STAGE(3, t);
    __syncthreads();                        // drains vmcnt(0): tile staged, all waves
    f16x8 af[4][2], bf[4][2];
    #pragma unroll
    for (int m = 0; m < 4; ++m)
      #pragma unroll
      for (int k = 0; k < 2; ++k) {
        af[m][k] = *(const f16x8*)(smem + aoffs[m][k]);
        bf[m][k] = *(const f16x8*)(smem + boffs[m][k]);
      }
    #pragma unroll
    for (int k = 0; k < 2; ++k)
      #pragma unroll
      for (int m = 0; m < 4; ++m)
        #pragma unroll
        for (int n = 0; n < 4; ++n)
          acc[m][n] = __builtin_amdgcn_mfma_f32_16x16x32_f16(af[m][k], bf[n][k], acc[m][n], 0, 0, 0);
    __syncthreads();                        // drains lgkmcnt: safe to overwrite LDS
  }

  // ---- epilogue: per-wave 8KB LDS region, swizzled conflict-free, coalesced stores
  float bv[4];
  #pragma unroll
  for (int n = 0; n < 4; ++n)
    bv[n] = (ks == 0) ? bias[e * N + nt * 128 + wc * 64 + n * 16 + ro] : 0.f;
  f16* Ct = (f16*)(smem + wv * 8192);       // [64][64] f16, col-byte ^= ((row>>2)&3)<<5
  #pragma unroll
  for (int m = 0; m < 4; ++m)
    #pragma unroll
    for (int n = 0; n < 4; ++n)
      #pragma unroll
      for (int i = 0; i < 4; ++i) {
        const int row = m * 16 + q4 + i;
        float v = acc[m][n][i] + bv[n];
        if (GELU) v = gelu_fast(v);
        *(f16*)((char*)Ct + row * 128 + (((n * 16 + ro) * 2) ^ (((row >> 2) & 3) << 5))) = (f16)v;
      }
  asm volatile("s_waitcnt lgkmcnt(0)" ::: "memory");
  __builtin_amdgcn_sched_barrier(0);
  f16* Cp = C + (size_t)ks * pstride;
  const size_t crow0 = (size_t)e * CAPD + mt * 128 + wr * 64;
  const int ccol0 = nt * 128 + wc * 64;
  #pragma unroll
  for (int j = 0; j < 8; ++j) {
    const int idx = j * 64 + lane;
    const int rr = idx >> 3, c2 = (idx & 7) * 16;
    f16x8 v = *(const f16x8*)((const char*)Ct + rr * 128 + (c2 ^ (((rr >> 2) & 3) << 5)));
    *(f16x8*)(Cp + (crow0 + rr) * N + ccol0 + (idx & 7) * 8) = v;
  }
}

// ---------------- combine: out[t] = sum_k wslot * (partA[row] + partB[row]) ----------------
__global__ void combine_k(const f16* __restrict__ pA, const f16* __restrict__ pB,
                          const int* __restrict__ eidx, const int* __restrict__ posa,
                          const float* __restrict__ wslot, float* __restrict__ out) {
  const int t = blockIdx.x, tid = threadIdx.x;
  const int s0 = 2 * t, s1 = 2 * t + 1;
  const int e0 = eidx[s0], e1 = eidx[s1];
  int p0 = posa[s0]; p0 = p0 < CAPD - 1 ? p0 : CAPD - 1;
  int p1 = posa[s1]; p1 = p1 < CAPD - 1 ? p1 : CAPD - 1;
  const float g0 = wslot[s0], g1 = wslot[s1];
  const size_t o0 = ((size_t)e0 * CAPD + p0) * DDIM;
  const size_t o1 = ((size_t)e1 * CAPD + p1) * DDIM;
  const f16x2* r0a = (const f16x2*)(pA + o0);
  const f16x2* r0b = (const f16x2*)(pB + o0);
  const f16x2* r1a = (const f16x2*)(pA + o1);
  const f16x2* r1b = (const f16x2*)(pB + o1);
  float2* o = (float2*)(out + (size_t)t * DDIM);
  #pragma unroll
  for (int j = tid; j < DDIM / 2; j += 256) {
    f16x2 a0 = r0a[j], a1 = r0b[j], b0 = r1a[j], b1 = r1b[j];
    o[j] = make_float2(
        g0 * ((float)a0.x + (float)a1.x) + g1 * ((float)b0.x + (float)b1.x),
        g0 * ((float)a0.y + (float)a1.y) + g1 * ((float)b0.y + (float)b1.y));
  }
}

extern "C" void kernel_launch(void* const* d_in, const int* in_sizes, int n_in,
                              void* d_out, int out_size, void* d_ws, size_t ws_size,
                              hipStream_t stream) {
  (void)in_sizes; (void)n_in; (void)out_size; (void)ws_size;
  const float* x  = (const float*)d_in[0];
  const float* rw = (const float*)d_in[1];
  const float* w1 = (const float*)d_in[2];
  const float* b1 = (const float*)d_in[3];
  const float* w2 = (const float*)d_in[4];
  const float* b2 = (const float*)d_in[5];
  float* out = (float*)d_out;

  char* ws = (char*)d_ws;
  size_t off = 0;
  auto alloc = [&](size_t b) { void* p = ws + off; off += (b + 255) & ~(size_t)255; return p; };
  f16* w1t   = (f16*)alloc((size_t)EDIM * DDIM * HDIM * 2);   // (E,H,D)
  f16* w2t   = (f16*)alloc((size_t)EDIM * DDIM * HDIM * 2);   // (E,D,H)
  f16* buf   = (f16*)alloc((size_t)EDIM * CAPD * DDIM * 2);   // (E,CAP,D)
  f16* hbuf  = (f16*)alloc((size_t)EDIM * CAPD * HDIM * 2);   // (E,CAP,H)
  const size_t PSTRIDE = (size_t)EDIM * CAPD * DDIM;
  f16* outeA = (f16*)alloc(PSTRIDE * 2);                       // split-K partial 0
  f16* outeB = (f16*)alloc(PSTRIDE * 2);                       // split-K partial 1 (contiguous)
  int*   eidx   = (int*)alloc(NSLOT * 4);
  int*   posa   = (int*)alloc(NSLOT * 4);
  float* gatesA = (float*)alloc(NSLOT * 4);
  float* wslotA = (float*)alloc(NSLOT * 4);
  int*   cc     = (int*)alloc(32 * EDIM * 4);
  int*   cb     = (int*)alloc(32 * EDIM * 4);
  int*   counts = (int*)alloc(EDIM * 4);
  int*   rowsN  = (int*)alloc(EDIM * 4);
  float* bps    = (float*)alloc(NROUTERBLK * EDIM * 4);
  (void)outeB;

  // weight conversion: both transposes, flat grid, gload_lds + swizzle (16384 tiles)
  transpose2_cvt<<<16384, 256, 0, stream>>>(w1, w1t, w2, w2t);

  // routing chain (split kernels — r17 showed merging serializes and loses 40 us)
  router_k<<<NROUTERBLK, 256, 0, stream>>>(x, rw, eidx, gatesA, bps);
  count_k<<<32, 256, 0, stream>>>(eidx, cc);
  scan_k<<<1, 256, 0, stream>>>(cc, bps, cb, counts, rowsN, out + (size_t)TDIM * DDIM);
  pos_k<<<32, 256, 0, stream>>>(eidx, gatesA, cb, posa, wslotA);
  scatter2_k<<<TDIM, 64, 0, stream>>>(x, eidx, posa, buf);

  // expert GEMM 1: (E,CAP,D) x (E,D,H) -> GELU -> (E,CAP,H)
  // banded grid: wg = e + 8*(ntl + 16*(mt + 16*nth)); NTH=16 (B half-set = 4MB = XCD L2)
  gemm128s<DDIM, DDIM, HDIM, 1, 16, 1, 16><<<4096, 256, 0, stream>>>(
      buf, w1t, b1, hbuf, 0, rowsN);

  // expert GEMM 2, split-K=2 in ONE dispatch; B set already L2-fits
  gemm128s<HDIM / 2, HDIM, DDIM, 0, 8, 2, 16><<<2048, 256, 0, stream>>>(
      hbuf, w2t, b2, outeA, PSTRIDE, rowsN);

  // combine
  combine_k<<<TDIM, 256, 0, stream>>>(outeA, outeA + PSTRIDE, eidx, posa, wslotA, out);
}